// Round 1
// 354.791 us; speedup vs baseline: 1.3645x; 1.3645x over previous
//
#include <hip/hip_runtime.h>
#include <math.h>

#define IMG_H 512
#define IMG_W 512
#define TS 32
#define NC 5
#define NB 8

__device__ __forceinline__ int reflect_idx(int i, int n) {
    if (i < 0) i = -i;
    if (i >= n) i = 2 * n - 2 - i;
    return i;
}

// ln(x) via native v_log_f32 (log2). rel err ~2^-21, fine vs 1.5e-2 tolerance.
__device__ __forceinline__ float fast_log(float x) {
    return __builtin_amdgcn_logf(x) * 0.6931471805599453f;
}

__device__ __forceinline__ float fast_asinh(float v) {
    float a = fabsf(v);
    float r = fast_log(a + __builtin_amdgcn_sqrtf(fmaf(a, a, 1.0f)));
    return copysignf(r, v);
}

__global__ __launch_bounds__(256)
void imnorm_kernel(const float* __restrict__ img, const float* __restrict__ bgr,
                   const float* __restrict__ thr, const float* __restrict__ scl,
                   float* __restrict__ out)
{
    const int plane = blockIdx.z;          // b*NC + c
    const int c = plane % NC;
    const int h0 = blockIdx.y * TS;
    const int w0 = blockIdx.x * TS;
    // reflection can only occur in the first/last block row/col (halo = 8 < TS)
    const bool edge_w = (w0 == 0) || (w0 + TS == IMG_W);
    const bool edge_h = (h0 == 0) || (h0 + TS == IMG_H);

    const float* x  = img + (size_t)plane * IMG_H * IMG_W;
    const float* bg = bgr + (size_t)plane * IMG_H * IMG_W;
    float* op = out + (size_t)plane * 7 * IMG_H * IMG_W;

    const int t = threadIdx.y * 32 + threadIdx.x;   // 0..255

    // +1 padded strides: sliding-window readers stride multiple columns per
    // lane; odd strides keep bank aliasing <= ~2-way.
    __shared__ float xs[48][49];        // x tile + halo 8
    __shared__ float rs[40][41];        // res = x - box_mean(x), tile + halo 4
    __shared__ float pool[48 * 41];     // h1 (48x41) overlaid with h2 (40x33):
    float (*h1)[41] = reinterpret_cast<float (*)[41]>(pool);  // dead after stage 3
    float (*h2)[33] = reinterpret_cast<float (*)[33]>(pool);  // born in stage 4

    // per-channel constants (15 floats, L2-resident)
    float s_thr[3], s_exp[3];
    #pragma unroll
    for (int j = 0; j < 3; ++j) {
        s_thr[j] = thr[c * 3 + j];
        s_exp[j] = __builtin_amdgcn_exp2f(scl[c * 3 + j] * 1.4426950408889634f);
    }

    // ---- stage 1: load x tile + halo (fast linear path for interior blocks) ----
    if (!edge_w && !edge_h) {
        const float* src = x + (size_t)(h0 - 8) * IMG_W + (w0 - 8);
        #pragma unroll
        for (int k = 0; k < 9; ++k) {           // 48*48 = 9*256
            int i = t + k * 256;
            int r = i / 48, cc = i - r * 48;
            xs[r][cc] = src[r * IMG_W + cc];
        }
    } else {
        #pragma unroll
        for (int k = 0; k < 9; ++k) {
            int i = t + k * 256;
            int r = i / 48, cc = i - r * 48;
            int gr = reflect_idx(h0 - 8 + r, IMG_H);
            int gc = reflect_idx(w0 - 8 + cc, IMG_W);
            xs[r][cc] = x[gr * IMG_W + gc];
        }
    }
    __syncthreads();

    // ---- stage 2: horizontal 9-sum of xs -> h1, sliding window ----
    // 48 rows x 5 segments of 8 outputs = 240 tasks
    if (t < 240) {
        const int r  = t / 5;
        const int c0 = (t - r * 5) * 8;
        float s = xs[r][c0];
        #pragma unroll
        for (int d = 1; d < 9; ++d) s += xs[r][c0 + d];
        h1[r][c0] = s;
        #pragma unroll
        for (int k = 1; k < 8; ++k) {
            s += xs[r][c0 + 8 + k] - xs[r][c0 + k - 1];
            h1[r][c0 + k] = s;
        }
    }
    __syncthreads();

    // ---- stage 3: vertical 9-sum -> res over tile+halo4, sliding window ----
    // 40 cols x 5 row-segments of 8 = 200 tasks. rs garbage only at
    // mirrored-out rows/cols, which stages 4/5 never read (they reflect back).
    if (t < 200) {
        const int seg = t / 40;
        const int cl  = t - seg * 40;
        const int r0  = seg * 8;
        float s = h1[r0][cl];
        #pragma unroll
        for (int d = 1; d < 9; ++d) s += h1[r0 + d][cl];
        rs[r0][cl] = xs[r0 + 4][cl + 4] - s * (1.0f / 81.0f);
        #pragma unroll
        for (int k = 1; k < 8; ++k) {
            s += h1[r0 + 8 + k][cl] - h1[r0 + k - 1][cl];
            rs[r0 + k][cl] = xs[r0 + k + 4][cl + 4] - s * (1.0f / 81.0f);
        }
    }
    __syncthreads();

    // ---- stage 4: horizontal 9-sum of res^2 -> h2 (reflect only on edge_w) ----
    if (!edge_w) {
        #pragma unroll
        for (int k = 0; k < 5; ++k) {           // 40*32 = 5*256
            int i = t + k * 256;
            int rr = i >> 5, wl = i & 31;
            float s = 0.f;
            #pragma unroll
            for (int d = 0; d < 9; ++d) {
                float v = rs[rr][wl + d];
                s = fmaf(v, v, s);
            }
            h2[rr][wl] = s;
        }
    } else {
        #pragma unroll
        for (int k = 0; k < 5; ++k) {
            int i = t + k * 256;
            int rr = i >> 5, wl = i & 31;
            float s = 0.f;
            #pragma unroll
            for (int d = 0; d < 9; ++d) {
                int mc = reflect_idx(w0 + wl - 4 + d, IMG_W) - (w0 - 4);  // in [0,40)
                float v = rs[rr][mc];
                s = fmaf(v, v, s);
            }
            h2[rr][wl] = s;
        }
    }
    __syncthreads();

    // ---- stage 5: vertical 9-sum (sliding; reflect only on edge_h) + elementwise ----
    const int wl  = threadIdx.x;
    const int hl0 = threadIdx.y * 4;            // 4 consecutive rows per thread

    // issue bg loads early to hide HBM latency under the LDS sums
    float bgv[4];
    #pragma unroll
    for (int k = 0; k < 4; ++k)
        bgv[k] = bg[(size_t)(h0 + hl0 + k) * IMG_W + (w0 + wl)];

    float ssum[4];
    if (!edge_h) {
        float s = h2[hl0][wl];
        #pragma unroll
        for (int d = 1; d < 9; ++d) s += h2[hl0 + d][wl];
        ssum[0] = s;
        #pragma unroll
        for (int k = 1; k < 4; ++k) {
            s += h2[hl0 + 8 + k][wl] - h2[hl0 + k - 1][wl];
            ssum[k] = s;
        }
    } else {
        #pragma unroll
        for (int k = 0; k < 4; ++k) {
            const int h = h0 + hl0 + k;
            float s = 0.f;
            #pragma unroll
            for (int d = 0; d < 9; ++d) {
                int mr = reflect_idx(h - 4 + d, IMG_H) - (h0 - 4);   // in [0,40)
                s += h2[mr][wl];
            }
            ssum[k] = s;
        }
    }

    const size_t chs = (size_t)IMG_H * IMG_W;
    #pragma unroll
    for (int k = 0; k < 4; ++k) {
        const int hl = hl0 + k;
        const int h = h0 + hl, w = w0 + wl;

        float stdev = __builtin_amdgcn_sqrtf(fmaxf(ssum[k], 0.0f) * (1.0f / 81.0f));
        float resv  = rs[hl + 4][wl + 4];
        float clahe = resv * __builtin_amdgcn_rcpf(fmaxf(stdev, 1.0f));

        float raw  = xs[hl + 8][wl + 8];
        float off0 = (raw - bgv[k]) * __builtin_amdgcn_rsqf(bgv[k]);
        float l0 = fast_log(fmaxf(off0 + 1.0f, 1.0f));   // t = 0
        float l1 = fast_log(fmaxf(off0, 1.0f));          // t = 1: (off0-1)+1

        const size_t base = (size_t)h * IMG_W + w;
        op[0 * chs + base] = raw;
        op[1 * chs + base] = l0;
        op[2 * chs + base] = l1;
        op[3 * chs + base] = clahe;
        #pragma unroll
        for (int j = 0; j < 3; ++j) {
            float v = (raw - s_thr[j]) * s_exp[j];
            op[(4 + j) * chs + base] = fast_asinh(v);
        }
    }
}

extern "C" void kernel_launch(void* const* d_in, const int* in_sizes, int n_in,
                              void* d_out, int out_size, void* d_ws, size_t ws_size,
                              hipStream_t stream) {
    const float* img = (const float*)d_in[0];
    const float* bg  = (const float*)d_in[1];
    const float* thr = (const float*)d_in[2];
    const float* scl = (const float*)d_in[3];
    float* out = (float*)d_out;

    dim3 grid(IMG_W / TS, IMG_H / TS, NB * NC);   // 16 x 16 x 40 = 10240 blocks
    dim3 block(32, 8);
    hipLaunchKernelGGL(imnorm_kernel, grid, block, 0, stream,
                       img, bg, thr, scl, out);
}